// Round 1
// baseline (357.031 us; speedup 1.0000x reference)
//
#include <hip/hip_runtime.h>
#include <math.h>

#define B 16
#define C 256
#define H 128
#define W 128
#define HW (H * W)      // 16384
#define HW4 (HW / 4)    // 4096 float4 chunks per image plane

// ---------------------------------------------------------------------------
// Kernel 1: channel-wise mean + max over C=256 for each (b, h, w).
// Layout: x[B, C, H, W]. Each thread owns one float4 (4 consecutive pixels);
// the block's 4 waves each reduce a 64-channel quarter, then combine via LDS.
// Wave loads are 64 lanes x 16 B contiguous = 1 KiB, perfectly coalesced.
// feat output: [B, 2, H, W]  (plane 0 = mean, plane 1 = max)
// ---------------------------------------------------------------------------
__global__ __launch_bounds__(256) void reduce_mean_max(
    const float* __restrict__ x, float* __restrict__ feat) {
  const int t    = threadIdx.x;
  const int lane = t & 63;
  const int cq   = t >> 6;                       // wave id = channel quarter
  const int chunk = blockIdx.x * 64 + lane;      // [0, 65536)
  const int b    = chunk >> 12;                  // 4096 chunks per image
  const int s4   = chunk & (HW4 - 1);

  const float4* xp = (const float4*)x + (size_t)(b * C + cq * 64) * HW4 + s4;

  float4 sum = make_float4(0.f, 0.f, 0.f, 0.f);
  float4 mx  = make_float4(-INFINITY, -INFINITY, -INFINITY, -INFINITY);
#pragma unroll 8
  for (int c = 0; c < 64; ++c) {
    float4 v = xp[(size_t)c * HW4];
    sum.x += v.x; sum.y += v.y; sum.z += v.z; sum.w += v.w;
    mx.x = fmaxf(mx.x, v.x); mx.y = fmaxf(mx.y, v.y);
    mx.z = fmaxf(mx.z, v.z); mx.w = fmaxf(mx.w, v.w);
  }

  __shared__ float4 s_sum[4][64];
  __shared__ float4 s_max[4][64];
  s_sum[cq][lane] = sum;
  s_max[cq][lane] = mx;
  __syncthreads();

  if (cq == 0) {
#pragma unroll
    for (int q = 1; q < 4; ++q) {
      float4 s2 = s_sum[q][lane];
      float4 m2 = s_max[q][lane];
      sum.x += s2.x; sum.y += s2.y; sum.z += s2.z; sum.w += s2.w;
      mx.x = fmaxf(mx.x, m2.x); mx.y = fmaxf(mx.y, m2.y);
      mx.z = fmaxf(mx.z, m2.z); mx.w = fmaxf(mx.w, m2.w);
    }
    const float inv = 1.0f / (float)C;
    float4 mean = make_float4(sum.x * inv, sum.y * inv, sum.z * inv, sum.w * inv);
    float4* fm = (float4*)feat + (size_t)(b * 2) * HW4 + s4;
    float4* fx = (float4*)feat + (size_t)(b * 2 + 1) * HW4 + s4;
    *fm = mean;
    *fx = mx;
  }
}

// ---------------------------------------------------------------------------
// Kernel 2: 3x3 conv (2 in-ch -> 1 out-ch, zero pad 1) + sigmoid.
// One thread per output pixel; weights (18 floats) staged in LDS.
// feat is 3 MB total traffic -> L2-resident, trivial cost.
// ---------------------------------------------------------------------------
__global__ __launch_bounds__(256) void conv3x3_sigmoid(
    const float* __restrict__ feat, const float* __restrict__ wgt,
    float* __restrict__ out) {
  __shared__ float sw[18];
  if (threadIdx.x < 18) sw[threadIdx.x] = wgt[threadIdx.x];
  __syncthreads();

  const int idx = blockIdx.x * 256 + threadIdx.x;  // [0, 262144)
  const int b = idx >> 14;
  const int s = idx & (HW - 1);
  const int h = s >> 7;
  const int w = s & (W - 1);

  float acc = 0.f;
#pragma unroll
  for (int ci = 0; ci < 2; ++ci) {
    const float* f  = feat + (size_t)(b * 2 + ci) * HW;
    const float* kw = sw + ci * 9;
#pragma unroll
    for (int dh = -1; dh <= 1; ++dh) {
      const int hh = h + dh;
      if (hh < 0 || hh >= H) continue;
      const float* row = f + hh * W;
#pragma unroll
      for (int dw = -1; dw <= 1; ++dw) {
        const int ww = w + dw;
        if (ww < 0 || ww >= W) continue;
        acc += row[ww] * kw[(dh + 1) * 3 + (dw + 1)];
      }
    }
  }
  out[idx] = 1.f / (1.f + expf(-acc));
}

extern "C" void kernel_launch(void* const* d_in, const int* in_sizes, int n_in,
                              void* d_out, int out_size, void* d_ws, size_t ws_size,
                              hipStream_t stream) {
  const float* x   = (const float*)d_in[0];   // [16, 256, 128, 128] fp32
  const float* wgt = (const float*)d_in[1];   // [1, 2, 3, 3] fp32
  float* out  = (float*)d_out;                // [16, 1, 128, 128] fp32
  float* feat = (float*)d_ws;                 // [16, 2, 128, 128] fp32 = 2 MB scratch

  // 65536 float4 chunks / 64 lanes = 1024 blocks
  reduce_mean_max<<<1024, 256, 0, stream>>>(x, feat);
  // 262144 outputs / 256 threads = 1024 blocks
  conv3x3_sigmoid<<<1024, 256, 0, stream>>>(feat, wgt, out);
}

// Round 3
// 347.614 us; speedup vs baseline: 1.0271x; 1.0271x over previous
//
#include <hip/hip_runtime.h>
#include <math.h>

#define B 16
#define C 256
#define H 128
#define W 128
#define HW (H * W)      // 16384
#define HW4 (HW / 4)    // 4096 float4 chunks per image plane

typedef float vfloat4 __attribute__((ext_vector_type(4)));  // builtin-compatible

// ---------------------------------------------------------------------------
// Kernel 1: channel-wise mean + max over C=256 for each (b, h, w).
// Layout: x[B, C, H, W]. Each thread owns one float4 (4 consecutive pixels);
// the block's 4 waves each reduce a 64-channel quarter, then combine via LDS.
// Wave loads are 64 lanes x 16 B contiguous = 1 KiB, coalesced. x is streamed
// once -> nontemporal loads to avoid polluting L2 (feat stays resident).
// feat output: [B, 2, H, W]  (plane 0 = mean, plane 1 = max)
// ---------------------------------------------------------------------------
__global__ __launch_bounds__(256, 4) void reduce_mean_max(
    const float* __restrict__ x, float* __restrict__ feat) {
  const int t    = threadIdx.x;
  const int lane = t & 63;
  const int cq   = t >> 6;                       // wave id = channel quarter
  const int chunk = blockIdx.x * 64 + lane;      // [0, 65536)
  const int b    = chunk >> 12;                  // 4096 chunks per image
  const int s4   = chunk & (HW4 - 1);

  const vfloat4* xp = (const vfloat4*)x + (size_t)(b * C + cq * 64) * HW4 + s4;

  vfloat4 sum = (vfloat4)(0.f);
  vfloat4 mx  = (vfloat4)(-INFINITY);
#pragma unroll 8
  for (int c = 0; c < 64; ++c) {
    vfloat4 v = __builtin_nontemporal_load(&xp[(size_t)c * HW4]);
    sum += v;
    mx.x = fmaxf(mx.x, v.x); mx.y = fmaxf(mx.y, v.y);
    mx.z = fmaxf(mx.z, v.z); mx.w = fmaxf(mx.w, v.w);
  }

  __shared__ vfloat4 s_sum[4][64];
  __shared__ vfloat4 s_max[4][64];
  s_sum[cq][lane] = sum;
  s_max[cq][lane] = mx;
  __syncthreads();

  // wave 0 writes the mean plane, wave 1 writes the max plane
  if (cq == 0) {
    vfloat4 a = s_sum[0][lane], b1 = s_sum[1][lane],
            c2 = s_sum[2][lane], d = s_sum[3][lane];
    const float inv = 1.0f / (float)C;
    vfloat4 mean = (a + b1 + c2 + d) * inv;
    ((vfloat4*)feat)[(size_t)(b * 2) * HW4 + s4] = mean;
  } else if (cq == 1) {
    vfloat4 a = s_max[0][lane], b1 = s_max[1][lane],
            c2 = s_max[2][lane], d = s_max[3][lane];
    vfloat4 m;
    m.x = fmaxf(fmaxf(a.x, b1.x), fmaxf(c2.x, d.x));
    m.y = fmaxf(fmaxf(a.y, b1.y), fmaxf(c2.y, d.y));
    m.z = fmaxf(fmaxf(a.z, b1.z), fmaxf(c2.z, d.z));
    m.w = fmaxf(fmaxf(a.w, b1.w), fmaxf(c2.w, d.w));
    ((vfloat4*)feat)[(size_t)(b * 2 + 1) * HW4 + s4] = m;
  }
}

// ---------------------------------------------------------------------------
// Kernel 2: 3x3 conv (2 in-ch -> 1 out-ch, zero pad 1) + sigmoid.
// One thread per output pixel; weights (18 floats) staged in LDS.
// feat is 3 MB total traffic -> L2/HBM trivial cost.
// ---------------------------------------------------------------------------
__global__ __launch_bounds__(256) void conv3x3_sigmoid(
    const float* __restrict__ feat, const float* __restrict__ wgt,
    float* __restrict__ out) {
  __shared__ float sw[18];
  if (threadIdx.x < 18) sw[threadIdx.x] = wgt[threadIdx.x];
  __syncthreads();

  const int idx = blockIdx.x * 256 + threadIdx.x;  // [0, 262144)
  const int b = idx >> 14;
  const int s = idx & (HW - 1);
  const int h = s >> 7;
  const int w = s & (W - 1);

  float acc = 0.f;
#pragma unroll
  for (int ci = 0; ci < 2; ++ci) {
    const float* f  = feat + (size_t)(b * 2 + ci) * HW;
    const float* kw = sw + ci * 9;
#pragma unroll
    for (int dh = -1; dh <= 1; ++dh) {
      const int hh = h + dh;
      if (hh < 0 || hh >= H) continue;
      const float* row = f + hh * W;
#pragma unroll
      for (int dw = -1; dw <= 1; ++dw) {
        const int ww = w + dw;
        if (ww < 0 || ww >= W) continue;
        acc += row[ww] * kw[(dh + 1) * 3 + (dw + 1)];
      }
    }
  }
  out[idx] = 1.f / (1.f + __expf(-acc));
}

extern "C" void kernel_launch(void* const* d_in, const int* in_sizes, int n_in,
                              void* d_out, int out_size, void* d_ws, size_t ws_size,
                              hipStream_t stream) {
  const float* x   = (const float*)d_in[0];   // [16, 256, 128, 128] fp32
  const float* wgt = (const float*)d_in[1];   // [1, 2, 3, 3] fp32
  float* out  = (float*)d_out;                // [16, 1, 128, 128] fp32
  float* feat = (float*)d_ws;                 // [16, 2, 128, 128] fp32 = 2 MB scratch

  // 65536 float4 chunks / 64 lanes = 1024 blocks
  reduce_mean_max<<<1024, 256, 0, stream>>>(x, feat);
  // 262144 outputs / 256 threads = 1024 blocks
  conv3x3_sigmoid<<<1024, 256, 0, stream>>>(feat, wgt, out);
}